// Round 1
// baseline (3439.813 us; speedup 1.0000x reference)
//
#include <hip/hip_runtime.h>
#include <math.h>

// ---------------- model constants ----------------
#define BATCH 65536
#define TB 64            // batch rows per block
#define SM 129           // stride of the MID-width (129) state buffer
#define SHH 65           // stride of the H-width (64) state buffer (65 = odd, conflict-free)
#define WA_ELEMS (64*9*129)   // 74304 merged-weight elems per 'a' layer ([I][9][O])
#define WB_ELEMS (129*9*64)   // 74304 per 'b' layer — same count

// ---------------------------------------------------------------------------
// setup: merge W'[(i,p),o] = ss[i,o]*coef[i,o,p] (p<8) | sb[i,o] (p==8)
// layout ws[layer][ (i*9+p)*O + o ]  -> coalesced on o in the hot loop
// ---------------------------------------------------------------------------
__global__ void setup_weights(
    const float* __restrict__ c0a, const float* __restrict__ b0a_, const float* __restrict__ s0a,
    const float* __restrict__ c0b, const float* __restrict__ b0b_, const float* __restrict__ s0b,
    const float* __restrict__ c1a, const float* __restrict__ b1a_, const float* __restrict__ s1a,
    const float* __restrict__ c1b, const float* __restrict__ b1b_, const float* __restrict__ s1b,
    float* __restrict__ ws) {
  int idx = blockIdx.x * blockDim.x + threadIdx.x;
  if (idx >= 4 * WA_ELEMS) return;
  int seg = idx / WA_ELEMS;
  int e   = idx - seg * WA_ELEMS;
  const float *coef, *sb, *ss; int O;
  switch (seg) {
    case 0:  coef=c0a; sb=b0a_; ss=s0a; O=129; break;
    case 1:  coef=c0b; sb=b0b_; ss=s0b; O=64;  break;
    case 2:  coef=c1a; sb=b1a_; ss=s1a; O=129; break;
    default: coef=c1b; sb=b1b_; ss=s1b; O=64;  break;
  }
  int o  = e % O;
  int pi = e / O;
  int p  = pi % 9;
  int i  = pi / 9;
  float v = (p < 8) ? ss[i*O+o] * coef[(i*O+o)*8 + p] : sb[i*O+o];
  ws[seg*WA_ELEMS + e] = v;
}

// ---------------------------------------------------------------------------
// features: 8 cubic B-spline basis values (uniform knots t_j = 0.4*j - 2.2,
// j=0..11) + silu. Interval m: t_m <= x < t_{m+1}; nonzero basis are
// j = m-3..m with the standard uniform cubic polynomials of u=(x-t_m)/0.4.
// Outside [-2.2, 2.2) everything is 0 (matches reference B0 indicators).
// ---------------------------------------------------------------------------
__device__ __forceinline__ void feat9(float x, float f[9]) {
  float s  = (x + 2.2f) * 2.5f;
  float mf = floorf(s);
  int   m  = (int)mf;
  float u  = s - mf;
  bool valid = (m >= 0) && (m <= 10);
  float u2 = u*u, u3 = u2*u;
  float um = 1.0f - u;
  float w0 = um*um*um * (1.0f/6.0f);
  float w1 = (3.0f*u3 - 6.0f*u2 + 4.0f) * (1.0f/6.0f);
  float w2 = (-3.0f*u3 + 3.0f*u2 + 3.0f*u + 1.0f) * (1.0f/6.0f);
  float w3 = u3 * (1.0f/6.0f);
  int j0 = m - 3;
  #pragma unroll
  for (int p = 0; p < 8; ++p) {
    int d = p - j0;
    float v = 0.0f;
    if (d == 0) v = w0;
    else if (d == 1) v = w1;
    else if (d == 2) v = w2;
    else if (d == 3) v = w3;
    f[p] = valid ? v : 0.0f;
  }
  f[8] = x / (1.0f + __expf(-x));   // silu
}

// ---------------------------------------------------------------------------
// one KAN layer on a 64-row tile.
//   I inputs (stride SIN in hin), O outputs (stride SOUT in hout)
//   OP = power-of-2 output slots handled by the main mapping (128 or 64)
//   R  = rows per thread = TB / (256/OP)
// thread t -> (o = t%OP, rowgroup rg = t/OP); o==128 (layer 'a') handled by
// threads t<64 (one row each) on the side.
// Features for a 4-input chunk staged in LDS as Fs[isub][p][row] so phase-B
// reads are float4 over rows (wave-uniform address -> LDS broadcast).
// ---------------------------------------------------------------------------
template<int I, int O, int OP, int R, int SIN, int SOUT>
__device__ void kan_layer_t(const float* __restrict__ hin, float* __restrict__ hout,
                            const float* __restrict__ wm, const float* __restrict__ bias,
                            float* __restrict__ Fs) {
  const int t  = threadIdx.x;
  const int o  = t % OP;
  const int rg = t / OP;
  float acc[R];
  #pragma unroll
  for (int j = 0; j < R; ++j) acc[j] = 0.0f;
  float acc128 = 0.0f;

  for (int i0 = 0; i0 < I; i0 += 4) {
    __syncthreads();   // previous chunk's readers of Fs are done
    {
      int r = t & 63, isub = t >> 6;
      if (i0 + isub < I) {
        float f9[9];
        feat9(hin[r*SIN + i0 + isub], f9);
        #pragma unroll
        for (int p = 0; p < 9; ++p) Fs[(isub*9 + p)*64 + r] = f9[p];
      }
    }
    __syncthreads();
    const int ci = (I - i0 < 4) ? (I - i0) : 4;
    for (int ii = 0; ii < ci; ++ii) {
      const int i = i0 + ii;
      float w[9];
      #pragma unroll
      for (int p = 0; p < 9; ++p) w[p] = wm[(i*9 + p)*O + o];
      #pragma unroll
      for (int p = 0; p < 9; ++p) {
        #pragma unroll
        for (int rv = 0; rv < R/4; ++rv) {
          const float4 f = *reinterpret_cast<const float4*>(&Fs[(ii*9 + p)*64 + rg*R + rv*4]);
          acc[rv*4+0] = fmaf(f.x, w[p], acc[rv*4+0]);
          acc[rv*4+1] = fmaf(f.y, w[p], acc[rv*4+1]);
          acc[rv*4+2] = fmaf(f.z, w[p], acc[rv*4+2]);
          acc[rv*4+3] = fmaf(f.w, w[p], acc[rv*4+3]);
        }
      }
      if (O > OP) {           // the odd 129th output, one row per thread t<64
        if (t < 64) {
          float s = 0.0f;
          #pragma unroll
          for (int p = 0; p < 9; ++p)
            s = fmaf(Fs[(ii*9 + p)*64 + t], wm[(i*9 + p)*O + OP], s);
          acc128 += s;
        }
      }
    }
  }
  const float b = bias[o];
  #pragma unroll
  for (int j = 0; j < R; ++j) hout[(rg*R + j)*SOUT + o] = acc[j] + b;
  if (O > OP) { if (t < 64) hout[t*SOUT + OP] = acc128 + bias[OP]; }
  __syncthreads();
}

// ---------------------------------------------------------------------------
// fused forward: x -> relu GEMM -> (a0,b0,a1,b1) KAN layers -> sigmoid GEMV
// LDS: hM (64x129 fp32, MID-width states + initial x), hH (64x65, H-width),
//      Fs (4x9x64 feature chunk)  => 58.9 KB -> 2 blocks/CU
// ---------------------------------------------------------------------------
extern "C" __global__ void __launch_bounds__(256, 2)
kan_forward(const float* __restrict__ x, const float* __restrict__ W_in,
            const float* __restrict__ b_in, const float* __restrict__ W_out,
            const float* __restrict__ ws,
            const float* __restrict__ bias0a, const float* __restrict__ bias0b,
            const float* __restrict__ bias1a, const float* __restrict__ bias1b,
            float* __restrict__ out) {
  __shared__ float hM[TB*SM];
  __shared__ float hH[TB*SHH];
  __shared__ float Fs[4*9*64];
  const int t  = threadIdx.x;
  const int r0 = blockIdx.x * TB;

  // stage 0: x tile -> hM[r][0..31]
  #pragma unroll
  for (int k = 0; k < 8; ++k) {
    int idx = t + k*256;               // 0..2047
    int r = idx >> 5, c = idx & 31;
    hM[r*SM + c] = x[(r0 + r)*32 + c];
  }
  __syncthreads();

  // stage 1: hH = relu(x @ W_in + b_in)   [64 out, 16 rows/thread]
  {
    const int o = t & 63, rg = t >> 6;
    float acc[16];
    #pragma unroll
    for (int j = 0; j < 16; ++j) acc[j] = 0.0f;
    for (int c = 0; c < 32; ++c) {
      float w = W_in[c*64 + o];
      #pragma unroll
      for (int j = 0; j < 16; ++j) acc[j] = fmaf(hM[(rg*16 + j)*SM + c], w, acc[j]);
    }
    float b = b_in[o];
    #pragma unroll
    for (int j = 0; j < 16; ++j) hH[(rg*16 + j)*SHH + o] = fmaxf(acc[j] + b, 0.0f);
  }
  // (kan_layer_t opens with __syncthreads before reading)

  kan_layer_t< 64,129,128,32, SHH, SM >(hH, hM, ws + 0*WA_ELEMS, bias0a, Fs);
  kan_layer_t<129, 64, 64,16, SM , SHH>(hM, hH, ws + 1*WA_ELEMS, bias0b, Fs);
  kan_layer_t< 64,129,128,32, SHH, SM >(hH, hM, ws + 2*WA_ELEMS, bias1a, Fs);
  kan_layer_t<129, 64, 64,16, SM , SHH>(hM, hH, ws + 3*WA_ELEMS, bias1b, Fs);

  // stage 5: out = sigmoid(hH @ W_out)   (W_out is [64,1])
  if (t < 64) {
    float s = 0.0f;
    #pragma unroll
    for (int c = 0; c < 64; ++c) s = fmaf(hH[t*SHH + c], W_out[c], s);
    out[r0 + t] = 1.0f / (1.0f + __expf(-s));
  }
}

// ---------------------------------------------------------------------------
extern "C" void kernel_launch(void* const* d_in, const int* in_sizes, int n_in,
                              void* d_out, int out_size, void* d_ws, size_t ws_size,
                              hipStream_t stream) {
  const float* x     = (const float*)d_in[0];
  const float* W_in  = (const float*)d_in[1];
  const float* b_in  = (const float*)d_in[2];
  const float* W_out = (const float*)d_in[3];
  const float* c0a = (const float*)d_in[4];  const float* sb0a = (const float*)d_in[5];
  const float* ss0a= (const float*)d_in[6];  const float* bias0a=(const float*)d_in[7];
  const float* c0b = (const float*)d_in[8];  const float* sb0b = (const float*)d_in[9];
  const float* ss0b= (const float*)d_in[10]; const float* bias0b=(const float*)d_in[11];
  const float* c1a = (const float*)d_in[12]; const float* sb1a = (const float*)d_in[13];
  const float* ss1a= (const float*)d_in[14]; const float* bias1a=(const float*)d_in[15];
  const float* c1b = (const float*)d_in[16]; const float* sb1b = (const float*)d_in[17];
  const float* ss1b= (const float*)d_in[18]; const float* bias1b=(const float*)d_in[19];
  float* out = (float*)d_out;
  float* ws  = (float*)d_ws;   // needs 4*74304*4 = 1,188,864 B of scratch

  const int total = 4 * WA_ELEMS;
  setup_weights<<<(total + 255)/256, 256, 0, stream>>>(
      c0a, sb0a, ss0a, c0b, sb0b, ss0b, c1a, sb1a, ss1a, c1b, sb1b, ss1b, ws);

  kan_forward<<<BATCH/TB, 256, 0, stream>>>(
      x, W_in, b_in, W_out, ws, bias0a, bias0b, bias1a, bias1b, out);
}

// Round 2
// 263.736 us; speedup vs baseline: 13.0426x; 13.0426x over previous
//
#include <hip/hip_runtime.h>
#include <math.h>

// ---------------- model constants ----------------
#define BATCH 65536
#define TB 64

typedef _Float16 half8  __attribute__((ext_vector_type(8)));
typedef float   floatx4 __attribute__((ext_vector_type(4)));

// LDS strides (elements)
#define SH 66     // hH stride (f16)  -> 66*2/4 = 33 banks, odd: conflict-free
#define SM 130    // hM stride (f16)  -> 65 banks, odd
#define FS 168    // F stride (f16)   -> 84 ≡ 20 (mod 32): 2-way max on b128 frags (free)
#define XS 33     // x fp32 scratch stride (aliased on F)

// packed-weight geometry: Wt[n][k] f16, k = spline (8 slots/i) then silu slots
#define KPA 576          // a-layer: 64*8 spline + 64 silu
#define KPB 1312         // b-layer: 144*8 spline (129 real) + 160 silu (129 real)
#define NPA 144          // a-layer O=129 padded to 9 n-tiles
#define NPB 64
#define WA (NPA*KPA)     // 82944
#define WB (NPB*KPB)     // 83968
#define WTOT (2*(WA+WB)) // 333824 halfs = 667648 B of d_ws

// ---------------------------------------------------------------------------
// setup: pack Wt[n][k] = ss[i,o]*coef[i,o,p] (spline, k=8i+p) | sb[i,o] (silu)
// zero outside real O / real I. Layout order: [a0 | b0 | a1 | b1].
// ---------------------------------------------------------------------------
__global__ void setup_weights(
    const float* __restrict__ c0a, const float* __restrict__ sb0a, const float* __restrict__ ss0a,
    const float* __restrict__ c0b, const float* __restrict__ sb0b, const float* __restrict__ ss0b,
    const float* __restrict__ c1a, const float* __restrict__ sb1a, const float* __restrict__ ss1a,
    const float* __restrict__ c1b, const float* __restrict__ sb1b, const float* __restrict__ ss1b,
    _Float16* __restrict__ wt) {
  int idx = blockIdx.x * 256 + threadIdx.x;
  if (idx >= WTOT) return;
  int pair = (idx >= WA + WB) ? 1 : 0;
  int e    = idx - pair * (WA + WB);
  const float *coef, *sb, *ss;
  float v = 0.0f;
  if (e < WA) {                       // a-type: I=64, O=129
    if (pair == 0) { coef = c0a; sb = sb0a; ss = ss0a; }
    else           { coef = c1a; sb = sb1a; ss = ss1a; }
    int n = e / KPA, k = e - n * KPA;
    if (n < 129) {
      if (k < 512) { int i = k >> 3, p = k & 7; v = ss[i*129+n] * coef[(i*129+n)*8 + p]; }
      else         { int i = k - 512;           v = sb[i*129+n]; }   // i < 64
    }
  } else {                            // b-type: I=129, O=64
    if (pair == 0) { coef = c0b; sb = sb0b; ss = ss0b; }
    else           { coef = c1b; sb = sb1b; ss = ss1b; }
    int eb = e - WA;
    int n = eb / KPB, k = eb - n * KPB;
    if (k < 1152) { int i = k >> 3, p = k & 7; if (i < 129) v = ss[i*64+n] * coef[(i*64+n)*8 + p]; }
    else          { int i = k - 1152;          if (i < 129) v = sb[i*64+n]; }
  }
  wt[idx] = (_Float16)v;
}

// ---------------------------------------------------------------------------
// 8 cubic B-spline basis values on the uniform extended grid t_j = 0.4j - 2.2
// (j=0..11). Writes the 4 nonzero weights into their slots, zeros elsewhere.
// Same polynomial math as the round-1 kernel (HW-verified, absmax 0.0039).
// ---------------------------------------------------------------------------
__device__ __forceinline__ void feat8_store(_Float16* dst, float x) {
  float s  = (x + 2.2f) * 2.5f;
  float mf = floorf(s);
  int   m  = (int)mf;
  float u  = s - mf;
  float u2 = u*u, u3 = u2*u;
  float um = 1.0f - u;
  float w0 = um*um*um * (1.0f/6.0f);
  float w1 = (3.0f*u3 - 6.0f*u2 + 4.0f) * (1.0f/6.0f);
  float w2 = (-3.0f*u3 + 3.0f*u2 + 3.0f*u + 1.0f) * (1.0f/6.0f);
  float w3 = u3 * (1.0f/6.0f);
  float4 z = {0.f, 0.f, 0.f, 0.f};
  *(float4*)dst = z;                  // zero all 8 f16 slots (16B, aligned)
  if (m >= 0 && m <= 10) {            // in-support; LDS ops in-order per lane
    int j0 = m - 3;
    float w[4] = {w0, w1, w2, w3};
    #pragma unroll
    for (int q = 0; q < 4; ++q) {
      int p = j0 + q;
      if (p >= 0 && p < 8) dst[p] = (_Float16)w[q];
    }
  }
}

// ---------------------------------------------------------------------------
// one KAN layer, MFMA path. 4 waves; wave owns an n-slice ({3,2,2,2} tiles for
// NT=9, 1 tile for NT=4) and loops all 4 m-tiles -> acc[4][MAXJ] f32x4.
// Spline features staged per 16-input chunk (128 k-slots) in F; silu staged
// as one SILK-slot chunk. A-frags: ds_read_b128 from F. B-frags: b128 from
// global Wt (L2-resident). All fragment layouts per cdna4 §3 (m120-verified).
// ---------------------------------------------------------------------------
template<int I, int O, int NT, int SPC, int SILK, int SIN, int SOUT, int KP>
__device__ __forceinline__ void kan_layer(
    const _Float16* __restrict__ hin, _Float16* __restrict__ hout,
    const _Float16* __restrict__ wt, const float* __restrict__ bias,
    _Float16* __restrict__ F) {
  const int t    = threadIdx.x;
  const int lane = t & 63;
  const int wv   = t >> 6;
  const int ln   = lane & 15;
  const int kq   = lane >> 4;
  constexpr int MAXJ = (NT == 9) ? 3 : 1;
  int nt0, ntc;
  if (NT == 9) { nt0 = (wv == 0) ? 0 : 2*wv + 1; ntc = (wv == 0) ? 3 : 2; }
  else         { nt0 = wv;                       ntc = 1; }

  floatx4 acc[4][MAXJ];
  #pragma unroll
  for (int m = 0; m < 4; ++m)
    #pragma unroll
    for (int j = 0; j < MAXJ; ++j) acc[m][j] = (floatx4){0.f, 0.f, 0.f, 0.f};

  const int row = lane;   // staging role: 64 rows x 4 i-subgroups
  const int ig  = wv;

  // ---- spline chunks: 16 inputs -> 128 k-slots each ----
  #pragma unroll 1
  for (int c = 0; c < SPC; ++c) {
    __syncthreads();                       // F free (prev chunk / prev layer done)
    #pragma unroll
    for (int j = 0; j < 4; ++j) {
      int il = ig*4 + j;                   // local input 0..15
      int i  = c*16 + il;
      float xv = (i < I) ? (float)hin[row*SIN + i] : 0.0f;  // pad inputs: w=0 anyway
      feat8_store(&F[row*FS + il*8], xv);
    }
    __syncthreads();
    #pragma unroll
    for (int kk = 0; kk < 4; ++kk) {
      half8 A[4];
      #pragma unroll
      for (int m = 0; m < 4; ++m)
        A[m] = *(const half8*)&F[(m*16 + ln)*FS + kk*32 + kq*8];
      #pragma unroll
      for (int j = 0; j < MAXJ; ++j) {
        if (NT == 9 && j >= ntc) continue;          // wave-uniform predicate
        const int n = (nt0 + j)*16 + ln;
        half8 B = *(const half8*)&wt[n*KP + c*128 + kk*32 + kq*8];
        #pragma unroll
        for (int m = 0; m < 4; ++m)
          acc[m][j] = __builtin_amdgcn_mfma_f32_16x16x32_f16(A[m], B, acc[m][j], 0, 0, 0);
      }
    }
  }

  // ---- silu chunk: SILK k-slots ----
  __syncthreads();
  for (int i = ig; i < SILK; i += 4) {
    float v = 0.0f;
    if (i < I) { float xv = (float)hin[row*SIN + i]; v = xv / (1.0f + __expf(-xv)); }
    F[row*FS + i] = (_Float16)v;
  }
  __syncthreads();
  #pragma unroll 1
  for (int kk = 0; kk < SILK/32; ++kk) {
    half8 A[4];
    #pragma unroll
    for (int m = 0; m < 4; ++m)
      A[m] = *(const half8*)&F[(m*16 + ln)*FS + kk*32 + kq*8];
    #pragma unroll
    for (int j = 0; j < MAXJ; ++j) {
      if (NT == 9 && j >= ntc) continue;
      const int n = (nt0 + j)*16 + ln;
      half8 B = *(const half8*)&wt[n*KP + SPC*128 + kk*32 + kq*8];
      #pragma unroll
      for (int m = 0; m < 4; ++m)
        acc[m][j] = __builtin_amdgcn_mfma_f32_16x16x32_f16(A[m], B, acc[m][j], 0, 0, 0);
    }
  }

  // ---- epilogue: C/D layout col=lane&15, row=(lane>>4)*4+reg (m89-verified) ----
  #pragma unroll
  for (int j = 0; j < MAXJ; ++j) {
    if (NT == 9 && j >= ntc) continue;
    const int col = (nt0 + j)*16 + ln;
    if (col < O) {
      const float bv = bias[col];
      #pragma unroll
      for (int m = 0; m < 4; ++m)
        #pragma unroll
        for (int r = 0; r < 4; ++r) {
          int rw = m*16 + kq*4 + r;
          hout[rw*SOUT + col] = (_Float16)(acc[m][j][r] + bv);
        }
    }
  }
}

// ---------------------------------------------------------------------------
// fused forward. LDS: hM 16.6K + hH 8.4K + F 21.5K = 46.6 KB -> 3 blocks/CU.
// ---------------------------------------------------------------------------
extern "C" __global__ void __launch_bounds__(256, 3)
kan_forward(const float* __restrict__ x, const float* __restrict__ W_in,
            const float* __restrict__ b_in, const float* __restrict__ W_out,
            const _Float16* __restrict__ wt,
            const float* __restrict__ bias0a, const float* __restrict__ bias0b,
            const float* __restrict__ bias1a, const float* __restrict__ bias1b,
            float* __restrict__ out) {
  __shared__ _Float16 hM[TB*SM];
  __shared__ _Float16 hH[TB*SH];
  __shared__ _Float16 F [TB*FS];
  const int t  = threadIdx.x;
  const int r0 = blockIdx.x * TB;

  // stage 0: x tile -> F (as fp32 scratch, stride 33)
  float* xs = (float*)F;
  #pragma unroll
  for (int k = 0; k < 8; ++k) {
    int idx = t + k*256;               // 0..2047
    int r = idx >> 5, c = idx & 31;
    xs[r*XS + c] = x[(r0 + r)*32 + c];
  }
  __syncthreads();

  // stage 1: hH = relu(x @ W_in + b_in), f16 out
  {
    const int o = t & 63, rg = t >> 6;
    float acc[16];
    #pragma unroll
    for (int j = 0; j < 16; ++j) acc[j] = 0.0f;
    for (int c = 0; c < 32; ++c) {
      float w = W_in[c*64 + o];
      #pragma unroll
      for (int j = 0; j < 16; ++j) acc[j] = fmaf(xs[(rg*16 + j)*XS + c], w, acc[j]);
    }
    float b = b_in[o];
    #pragma unroll
    for (int j = 0; j < 16; ++j)
      hH[(rg*16 + j)*SH + o] = (_Float16)fmaxf(acc[j] + b, 0.0f);
  }
  // each kan_layer opens with __syncthreads() before touching F

  kan_layer< 64,129,9,4, 64,SH,SM,KPA>(hH, hM, wt,             bias0a, F);
  kan_layer<129, 64,4,9,160,SM,SH,KPB>(hM, hH, wt + WA,        bias0b, F);
  kan_layer< 64,129,9,4, 64,SH,SM,KPA>(hH, hM, wt + WA + WB,   bias1a, F);
  kan_layer<129, 64,4,9,160,SM,SH,KPB>(hM, hH, wt + 2*WA + WB, bias1b, F);

  __syncthreads();
  // stage 5: out = sigmoid(hH @ W_out), W_out is [64,1]
  if (t < 64) {
    float s = 0.0f;
    #pragma unroll
    for (int c = 0; c < 64; ++c) s = fmaf((float)hH[t*SH + c], W_out[c], s);
    out[r0 + t] = 1.0f / (1.0f + __expf(-s));
  }
}

// ---------------------------------------------------------------------------
extern "C" void kernel_launch(void* const* d_in, const int* in_sizes, int n_in,
                              void* d_out, int out_size, void* d_ws, size_t ws_size,
                              hipStream_t stream) {
  const float* x     = (const float*)d_in[0];
  const float* W_in  = (const float*)d_in[1];
  const float* b_in  = (const float*)d_in[2];
  const float* W_out = (const float*)d_in[3];
  const float* c0a = (const float*)d_in[4];  const float* sb0a = (const float*)d_in[5];
  const float* ss0a= (const float*)d_in[6];  const float* bias0a=(const float*)d_in[7];
  const float* c0b = (const float*)d_in[8];  const float* sb0b = (const float*)d_in[9];
  const float* ss0b= (const float*)d_in[10]; const float* bias0b=(const float*)d_in[11];
  const float* c1a = (const float*)d_in[12]; const float* sb1a = (const float*)d_in[13];
  const float* ss1a= (const float*)d_in[14]; const float* bias1a=(const float*)d_in[15];
  const float* c1b = (const float*)d_in[16]; const float* sb1b = (const float*)d_in[17];
  const float* ss1b= (const float*)d_in[18]; const float* bias1b=(const float*)d_in[19];
  float*     out = (float*)d_out;
  _Float16*  wt  = (_Float16*)d_ws;     // 667,648 B of scratch (ws re-poisoned each call; repacked each call)

  setup_weights<<<(WTOT + 255)/256, 256, 0, stream>>>(
      c0a, sb0a, ss0a, c0b, sb0b, ss0b, c1a, sb1a, ss1a, c1b, sb1b, ss1b, wt);

  kan_forward<<<BATCH/TB, 256, 0, stream>>>(
      x, W_in, b_in, W_out, wt, bias0a, bias0b, bias1a, bias1b, out);
}